// Round 2
// baseline (2946.258 us; speedup 1.0000x reference)
//
#include <hip/hip_runtime.h>

typedef unsigned short u16;
typedef unsigned int   u32;

// ---------- scalar/vec conversion helpers ----------
__device__ __forceinline__ float bf2f(u16 v) {
    return __uint_as_float(((u32)v) << 16);
}
__device__ __forceinline__ u16 f2bf(float f) {
    u32 u = __float_as_uint(f);
    u32 r = (u + 0x7fffu + ((u >> 16) & 1u)) >> 16;  // round-to-nearest-even
    return (u16)r;
}
__device__ __forceinline__ void unpack8(uint4 u, float* f) {
    f[0] = __uint_as_float(u.x << 16); f[1] = __uint_as_float(u.x & 0xffff0000u);
    f[2] = __uint_as_float(u.y << 16); f[3] = __uint_as_float(u.y & 0xffff0000u);
    f[4] = __uint_as_float(u.z << 16); f[5] = __uint_as_float(u.z & 0xffff0000u);
    f[6] = __uint_as_float(u.w << 16); f[7] = __uint_as_float(u.w & 0xffff0000u);
}
// 16 contiguous elements -> float[16], overloaded on storage type
__device__ __forceinline__ void load16(const u16* p, float* f) {
    unpack8(*(const uint4*)p, f);
    unpack8(*(const uint4*)(p + 8), f + 8);
}
__device__ __forceinline__ void load16(const float* p, float* f) {
    const float4* q = (const float4*)p;
    float4 a = q[0], b = q[1], c = q[2], d = q[3];
    f[0]=a.x; f[1]=a.y; f[2]=a.z; f[3]=a.w;
    f[4]=b.x; f[5]=b.y; f[6]=b.z; f[7]=b.w;
    f[8]=c.x; f[9]=c.y; f[10]=c.z; f[11]=c.w;
    f[12]=d.x; f[13]=d.y; f[14]=d.z; f[15]=d.w;
}
__device__ __forceinline__ float ld1(const u16* p)   { return bf2f(*p); }
__device__ __forceinline__ float ld1(const float* p) { return *p; }

// ---------- problem constants ----------
#define BB 4
#define NTOK 2048
#define NATOM 16384
#define CTOK 384
#define CA 128
#define NQ 32
#define NK 128
#define NH 4
#define DH 32
#define NWIN 512
#define PAD 48

// =====================================================================
// dtype detector: look at low u16 of 1024 words of W_a.
// bf16 storage -> low u16 is a bf16 with sane exponent (~100% in range)
// f32 storage  -> low u16 is random mantissa bits (~16% in range)
// flag = 1 (bf16 inputs) or 0 (f32 inputs)
// =====================================================================
__global__ __launch_bounds__(256) void detect_kernel(const u32* __restrict__ wa,
                                                     int* __restrict__ flag)
{
    __shared__ int cnt;
    if (threadIdx.x == 0) cnt = 0;
    __syncthreads();
    int local = 0;
#pragma unroll
    for (int i = 0; i < 4; i++) {
        u32 w = wa[threadIdx.x * 4 + i];
        u32 e = (w >> 7) & 0xFFu;   // exponent field of the LOW u16 as bf16
        if (e >= 95u && e <= 135u) local++;
    }
    atomicAdd(&cnt, local);
    __syncthreads();
    if (threadIdx.x == 0) *flag = (cnt >= 614) ? 1 : 0;
}

// =====================================================================
// Generic GEMM: C[*, ccol..+127] (+)= op(A[*, :K] @ W[:, wcol..+127])
// Tile 128x128, 256 threads, 8x8 accum per thread. K % 32 == 0.
// =====================================================================
#define GKC 32
#define GLDS 132

template<typename TA, typename TW, bool OUT_BF16, bool ADD, bool RELU>
__global__ __launch_bounds__(256) void gemm128(
    const int* __restrict__ flag, int want,
    const TA* __restrict__ A, int lda,
    const TW* __restrict__ W, int ldw, int wc0,
    void* __restrict__ Cv, int ldc, int cc0,
    int K)
{
    if (*flag != want) return;
    __shared__ float As[GKC][GLDS];   // [k][m]
    __shared__ float Ws[GKC][GLDS];   // [k][n]
    const int tid  = threadIdx.x;
    const int row0 = blockIdx.x * 128;
    const int cch  = blockIdx.y * 128;
    const int wcol = wc0 + cch;
    const int ccol = cc0 + cch;
    const int ty = tid >> 4, tx = tid & 15;

    float acc[8][8];
#pragma unroll
    for (int i = 0; i < 8; i++)
#pragma unroll
        for (int j = 0; j < 8; j++) acc[i][j] = 0.f;

    const int m_l = tid >> 1;          // 0..127
    const int ak0 = (tid & 1) << 4;    // 0 / 16
    const int w_k = tid >> 3;          // 0..31
    const int wcc = (tid & 7) << 4;    // 0..112

    for (int kc = 0; kc < K; kc += GKC) {
        float av16[16], wv16[16];
        load16(A + (size_t)(row0 + m_l) * lda + kc + ak0, av16);
        load16(W + (size_t)(kc + w_k) * ldw + wcol + wcc, wv16);
        __syncthreads();   // previous iteration's compute done
#pragma unroll
        for (int j = 0; j < 16; j++) As[ak0 + j][m_l] = av16[j];
#pragma unroll
        for (int j = 0; j < 16; j++) Ws[w_k][wcc + j] = wv16[j];
        __syncthreads();

        for (int k = 0; k < GKC; k++) {
            const float4 a0 = *(const float4*)&As[k][ty << 3];
            const float4 a1 = *(const float4*)&As[k][(ty << 3) + 4];
            const float4 w0 = *(const float4*)&Ws[k][tx << 3];
            const float4 w1 = *(const float4*)&Ws[k][(tx << 3) + 4];
            const float a[8]  = {a0.x, a0.y, a0.z, a0.w, a1.x, a1.y, a1.z, a1.w};
            const float wv[8] = {w0.x, w0.y, w0.z, w0.w, w1.x, w1.y, w1.z, w1.w};
#pragma unroll
            for (int i = 0; i < 8; i++)
#pragma unroll
                for (int j = 0; j < 8; j++)
                    acc[i][j] = fmaf(a[i], wv[j], acc[i][j]);
        }
    }

#pragma unroll
    for (int i = 0; i < 8; i++) {
        const size_t r = (size_t)row0 + (ty << 3) + i;
        if (OUT_BF16) {
            union { u16 s[8]; uint4 v; } pk;
#pragma unroll
            for (int j = 0; j < 8; j++) {
                float v = acc[i][j];
                if (RELU) v = fmaxf(v, 0.f);
                pk.s[j] = f2bf(v);
            }
            *(uint4*)((u16*)Cv + r * ldc + ccol + (tx << 3)) = pk.v;
        } else {
            float* C = (float*)Cv + r * ldc + ccol + (tx << 3);
            float4 c0, c1;
            if (ADD) { c0 = ((const float4*)C)[0]; c1 = ((const float4*)C)[1]; }
            else     { c0 = make_float4(0,0,0,0);  c1 = make_float4(0,0,0,0); }
            c0.x += acc[i][0]; c0.y += acc[i][1]; c0.z += acc[i][2]; c0.w += acc[i][3];
            c1.x += acc[i][4]; c1.y += acc[i][5]; c1.z += acc[i][6]; c1.w += acc[i][7];
            ((float4*)C)[0] = c0; ((float4*)C)[1] = c1;
        }
    }
}

// =====================================================================
// Gather: x[b,n,:] = a_tok[b, idx[b,n], :]   (f32 -> f32)
// =====================================================================
__global__ __launch_bounds__(256) void gather_kernel(
    const int* __restrict__ flag, int want,
    const float* __restrict__ a_tok, const int* __restrict__ idx,
    float* __restrict__ x)
{
    if (*flag != want) return;
    const size_t i = (size_t)blockIdx.x * 256 + threadIdx.x;  // B*N*128 total
    const int c = (int)(i & 127);
    const size_t an = i >> 7;
    const int b = (int)(an >> 14);
    const int n = (int)(an & (NATOM - 1));
    const int t = idx[b * NATOM + n];
    x[i] = a_tok[(((size_t)b * NTOK) + t) * CA + c];
}

// =====================================================================
// LayerNorm: h = (x-m)*rsqrt(var+1e-5)*g + b   (f32 in, bf16 out)
// =====================================================================
template<typename TW>
__global__ __launch_bounds__(256) void ln_kernel(
    const int* __restrict__ flag, int want,
    const float* __restrict__ x, const TW* __restrict__ g,
    const TW* __restrict__ b, u16* __restrict__ h)
{
    if (*flag != want) return;
    const int lane = threadIdx.x & 63;
    const int wv   = threadIdx.x >> 6;
    const size_t atom = (size_t)blockIdx.x * 4 + wv;
    const float* xr = x + atom * CA;
    const float v0 = xr[lane], v1 = xr[lane + 64];
    float s  = v0 + v1;
    float sq = v0 * v0 + v1 * v1;
#pragma unroll
    for (int off = 32; off > 0; off >>= 1) {
        s  += __shfl_xor(s,  off, 64);
        sq += __shfl_xor(sq, off, 64);
    }
    const float mean = s * 0.0078125f;
    const float var  = sq * 0.0078125f - mean * mean;
    const float inv  = rsqrtf(var + 1e-5f);
    u16* hr = h + atom * CA;
    hr[lane]      = f2bf((v0 - mean) * inv * ld1(g + lane)      + ld1(b + lane));
    hr[lane + 64] = f2bf((v1 - mean) * inv * ld1(g + lane + 64) + ld1(b + lane + 64));
}

// =====================================================================
// Bias: t[b,a,h] for a < 128 from the pair-MLP; single block, 512 threads
// =====================================================================
template<typename TW>
__global__ __launch_bounds__(512) void bias_kernel(
    const int* __restrict__ flag, int want,
    const float* __restrict__ x,
    const TW* __restrict__ Wcl, const TW* __restrict__ Wcm,
    const TW* __restrict__ Wm1, const TW* __restrict__ Wm2,
    const TW* __restrict__ Wpb, float* __restrict__ tb)
{
    if (*flag != want) return;
    __shared__ float Wsum[128][16];
    __shared__ float M1[16][16];
    __shared__ float M2[16][16];
    __shared__ float Pb[16][4];
    const int tid = threadIdx.x;
    for (int i = tid; i < 128 * 16; i += 512)
        Wsum[i >> 4][i & 15] = ld1(Wcl + i) + ld1(Wcm + i);
    if (tid < 256) M1[tid >> 4][tid & 15] = ld1(Wm1 + tid);
    if (tid >= 256 && tid < 512) { int t2 = tid - 256; M2[t2 >> 4][t2 & 15] = ld1(Wm2 + t2); }
    if (tid < 64) Pb[tid >> 2][tid & 3] = ld1(Wpb + tid);
    __syncthreads();

    const int b = tid >> 7, a = tid & 127;
    const float* xa = x + ((size_t)b * NATOM + a) * CA;
    float u[16];
#pragma unroll
    for (int p = 0; p < 16; p++) u[p] = 0.f;
    for (int c = 0; c < 128; c++) {
        const float xv = xa[c];
#pragma unroll
        for (int p = 0; p < 16; p++) u[p] = fmaf(xv, Wsum[c][p], u[p]);
    }
    float r1[16];
#pragma unroll
    for (int p = 0; p < 16; p++) r1[p] = 0.f;
    for (int c = 0; c < 16; c++) {
        const float rv = fmaxf(u[c], 0.f);
#pragma unroll
        for (int p = 0; p < 16; p++) r1[p] = fmaf(rv, M1[c][p], r1[p]);
    }
    float r2[16];
#pragma unroll
    for (int p = 0; p < 16; p++) r2[p] = 0.f;
    for (int c = 0; c < 16; c++) {
        const float rv = fmaxf(r1[c], 0.f);
#pragma unroll
        for (int p = 0; p < 16; p++) r2[p] = fmaf(rv, M2[c][p], r2[p]);
    }
#pragma unroll
    for (int hh = 0; hh < 4; hh++) {
        float s = 0.f;
#pragma unroll
        for (int p = 0; p < 16; p++) s = fmaf(r2[p], Pb[p][hh], s);
        tb[(size_t)tid * 4 + hh] = s;
    }
}

// =====================================================================
// Windowed attention: one block per (b, w).
// =====================================================================
__global__ __launch_bounds__(256) void attn_kernel(
    const int* __restrict__ flag, int want,
    const u16* __restrict__ qg, const u16* __restrict__ kg,
    const u16* __restrict__ vg, const float* __restrict__ tb,
    u16* __restrict__ og)
{
    if (*flag != want) return;
    __shared__ float ks[128][33];
    __shared__ float vs[128][33];
    __shared__ float qs[32][33];
    __shared__ float sc[32][129];
    __shared__ float tL[128];
    __shared__ float inv[32];
    __shared__ int   validv[128];

    const int tid = threadIdx.x;
    const int b = blockIdx.x >> 9;
    const int w = blockIdx.x & (NWIN - 1);
    const float scale = 0.17677669529663687f;  // 1/sqrt(32)

    for (int h = 0; h < NH; h++) {
        {   // stage K and V (zero invalid rows)
            const int j  = tid >> 1;
            const int d0 = (tid & 1) << 4;
            const int ga = w * NQ + j - PAD;
            const bool val = (ga >= 0) && (ga < NATOM);
            float kf[16], vf[16];
            if (val) {
                load16(kg + (((size_t)b * NATOM + ga) * CA) + h * DH + d0, kf);
                load16(vg + (((size_t)b * NATOM + ga) * CA) + h * DH + d0, vf);
            } else {
#pragma unroll
                for (int t2 = 0; t2 < 16; t2++) { kf[t2] = 0.f; vf[t2] = 0.f; }
            }
#pragma unroll
            for (int t2 = 0; t2 < 16; t2++) { ks[j][d0 + t2] = kf[t2]; vs[j][d0 + t2] = vf[t2]; }
            if (d0 == 0) validv[j] = val ? 1 : 0;
        }
        if (tid < 64) {  // stage Q
            const int qi = tid >> 1;
            const int d0 = (tid & 1) << 4;
            float qf[16];
            load16(qg + (((size_t)b * NATOM + w * NQ + qi) * CA) + h * DH + d0, qf);
#pragma unroll
            for (int t2 = 0; t2 < 16; t2++) qs[qi][d0 + t2] = qf[t2];
        }
        if (tid < 128) tL[tid] = tb[((size_t)b * 128 + tid) * 4 + h];
        __syncthreads();

        {   // scores
            const int j  = tid & 127;
            const int qh = tid >> 7;
            for (int qi = qh; qi < NQ; qi += 2) {
                float s = 0.f;
#pragma unroll
                for (int d = 0; d < DH; d++) s = fmaf(qs[qi][d], ks[j][d], s);
                sc[qi][j] = validv[j] ? (s * scale + tL[qi] + tL[j]) : -1e9f;
            }
        }
        __syncthreads();
        if (tid < 32) {  // softmax per query row
            const int qi = tid;
            float m = -1e30f;
            for (int j = 0; j < NK; j++) m = fmaxf(m, sc[qi][j]);
            float sum = 0.f;
            for (int j = 0; j < NK; j++) {
                const float e = __expf(sc[qi][j] - m);
                sc[qi][j] = e;
                sum += e;
            }
            inv[qi] = 1.0f / sum;
        }
        __syncthreads();
        {   // o = attn @ v
            const int d  = tid & 31;
            const int qg2 = tid >> 5;   // 0..7
#pragma unroll
            for (int i2 = 0; i2 < 4; i2++) {
                const int qi = qg2 * 4 + i2;
                float a = 0.f;
                for (int j = 0; j < NK; j++) a = fmaf(sc[qi][j], vs[j][d], a);
                og[(((size_t)b * NATOM) + w * NQ + qi) * CA + h * DH + d] = f2bf(a * inv[qi]);
            }
        }
        __syncthreads();
    }
}

// =====================================================================
// Final selector: write d_out as bf16 (flag=1) or f32 (flag=0)
// =====================================================================
__global__ __launch_bounds__(256) void select_kernel(
    const int* __restrict__ flag,
    const u16* __restrict__ outA, const u16* __restrict__ outB,
    void* __restrict__ d_out)
{
    const size_t i = (size_t)blockIdx.x * 256 + threadIdx.x;
    if (*flag) ((u16*)d_out)[i]   = outA[i];
    else       ((float*)d_out)[i] = bf2f(outB[i]);
}

// =====================================================================
// One full pipeline pass, templated on input storage type, gated on flag
// =====================================================================
template<typename TIN>
static void run_pass(void* const* d_in,
                     float* x, u16* h, u16* qb, u16* kb, u16* vb, u16* ob,
                     float* atok, u16* hidc, float* tbv, u16* outbuf,
                     const int* flag, int want, hipStream_t stream)
{
    const TIN* a    = (const TIN*)d_in[0];
    const int* idx  = (const int*)d_in[2];
    const TIN* W_a  = (const TIN*)d_in[3];
    const TIN* W_o  = (const TIN*)d_in[4];
    const TIN* Wcl  = (const TIN*)d_in[5];
    const TIN* Wcm  = (const TIN*)d_in[6];
    const TIN* Wm1  = (const TIN*)d_in[7];
    const TIN* Wm2  = (const TIN*)d_in[8];
    const TIN* Wpb  = (const TIN*)d_in[9];
    const TIN* Wq   = (const TIN*)d_in[10];
    const TIN* Wk   = (const TIN*)d_in[11];
    const TIN* Wv   = (const TIN*)d_in[12];
    const TIN* Wo   = (const TIN*)d_in[13];
    const TIN* ln1g = (const TIN*)d_in[14];
    const TIN* ln1b = (const TIN*)d_in[15];
    const TIN* Wt1  = (const TIN*)d_in[16];
    const TIN* Wt2  = (const TIN*)d_in[17];
    const TIN* ln2g = (const TIN*)d_in[18];
    const TIN* ln2b = (const TIN*)d_in[19];

    const size_t NEL = (size_t)BB * NATOM * CA;

    // token projection [8192 x 384] @ [384 x 128] -> f32 atok
    gemm128<TIN, TIN, false, false, false><<<64, 256, 0, stream>>>(
        flag, want, a, CTOK, W_a, CA, 0, atok, CA, 0, CTOK);
    gather_kernel<<<(unsigned)(NEL / 256), 256, 0, stream>>>(flag, want, atok, idx, x);
    bias_kernel<TIN><<<1, 512, 0, stream>>>(flag, want, x, Wcl, Wcm, Wm1, Wm2, Wpb, tbv);

    for (int l = 0; l < 3; l++) {
        const size_t wofs = (size_t)l * CA * CA;
        const size_t tofs = (size_t)l * CA * 512;   // same element count for Wt1/Wt2 blocks
        ln_kernel<TIN><<<BB * NATOM / 4, 256, 0, stream>>>(flag, want, x, ln1g + l * CA, ln1b + l * CA, h);
        gemm128<u16, TIN, true, false, false><<<512, 256, 0, stream>>>(flag, want, h, CA, Wq + wofs, CA, 0, qb, CA, 0, CA);
        gemm128<u16, TIN, true, false, false><<<512, 256, 0, stream>>>(flag, want, h, CA, Wk + wofs, CA, 0, kb, CA, 0, CA);
        gemm128<u16, TIN, true, false, false><<<512, 256, 0, stream>>>(flag, want, h, CA, Wv + wofs, CA, 0, vb, CA, 0, CA);
        attn_kernel<<<BB * NWIN, 256, 0, stream>>>(flag, want, qb, kb, vb, tbv, ob);
        gemm128<u16, TIN, false, true, false><<<512, 256, 0, stream>>>(flag, want, ob, CA, Wo + wofs, CA, 0, x, CA, 0, CA);
        ln_kernel<TIN><<<BB * NATOM / 4, 256, 0, stream>>>(flag, want, x, ln2g + l * CA, ln2b + l * CA, h);
        // MLP in 4 column chunks: x += relu(h @ Wt1[:,c*128..]) @ Wt2[c*128..,:]
        for (int c = 0; c < 4; c++) {
            gemm128<u16, TIN, true, false, true><<<512, 256, 0, stream>>>(
                flag, want, h, CA, Wt1 + tofs, 512, c * 128, hidc, CA, 0, CA);
            gemm128<u16, TIN, false, true, false><<<512, 256, 0, stream>>>(
                flag, want, hidc, CA, Wt2 + tofs + (size_t)c * 128 * CA, CA, 0, x, CA, 0, CA);
        }
    }
    // out = x @ W_out -> bf16 outbuf
    gemm128<float, TIN, true, false, false><<<512, 256, 0, stream>>>(
        flag, want, x, CA, W_o, CA, 0, outbuf, CA, 0, CA);
}

// =====================================================================
// Launch
// =====================================================================
extern "C" void kernel_launch(void* const* d_in, const int* in_sizes, int n_in,
                              void* d_out, int out_size, void* d_ws, size_t ws_size,
                              hipStream_t stream)
{
    (void)in_sizes; (void)n_in; (void)out_size;
    const size_t NEL = (size_t)BB * NATOM * CA;   // 8388608

    char* p = (char*)d_ws;
    float* x    = (float*)p;  p += NEL * 4;
    u16*   h    = (u16*)p;    p += NEL * 2;
    u16*   qb   = (u16*)p;    p += NEL * 2;
    u16*   kb   = (u16*)p;    p += NEL * 2;
    u16*   vb   = (u16*)p;    p += NEL * 2;
    u16*   ob   = (u16*)p;    p += NEL * 2;
    float* atok = (float*)p;  p += (size_t)BB * NTOK * CA * 4;
    u16*   hidc = (u16*)p;    p += NEL * 2;
    float* tbv  = (float*)p;  p += 8192;
    u16*   outA = (u16*)p;    p += NEL * 2;
    u16*   outB = (u16*)p;    p += NEL * 2;
    int*   flag = (int*)p;    p += 256;
    if ((size_t)(p - (char*)d_ws) > ws_size) return;  // workspace too small

    // 1) detect input storage dtype (writes flag: 1=bf16, 0=f32)
    detect_kernel<<<1, 256, 0, stream>>>((const u32*)d_in[3], flag);
    // 2) bf16-interpretation pass (runs only if flag==1)
    run_pass<u16>(d_in, x, h, qb, kb, vb, ob, atok, hidc, tbv, outA, flag, 1, stream);
    // 3) f32-interpretation pass (runs only if flag==0)
    run_pass<float>(d_in, x, h, qb, kb, vb, ob, atok, hidc, tbv, outB, flag, 0, stream);
    // 4) write d_out in the detected output format
    select_kernel<<<(unsigned)(NEL / 256), 256, 0, stream>>>(flag, outA, outB, d_out);
}